// Round 3
// baseline (662.337 us; speedup 1.0000x reference)
//
#include <hip/hip_runtime.h>

typedef __attribute__((ext_vector_type(8))) short bf16x8;
typedef __attribute__((ext_vector_type(4))) float f32x4;
typedef __attribute__((ext_vector_type(4))) unsigned int u32x4;

__device__ __forceinline__ unsigned short f2bf(float f) {
    union { float f; unsigned int u; } v; v.f = f;
    return (unsigned short)((v.u + 0x7fffu + ((v.u >> 16) & 1u)) >> 16);
}
__device__ __forceinline__ float bflo(unsigned int u) {
    union { unsigned int u; float f; } v; v.u = u << 16; return v.f;
}
__device__ __forceinline__ float bfhi(unsigned int u) {
    union { unsigned int u; float f; } v; v.u = u & 0xffff0000u; return v.f;
}
__device__ __forceinline__ float bfu(unsigned short s) {
    union { unsigned int u; float f; } v; v.u = ((unsigned int)s) << 16; return v.f;
}

// ---------------------------------------------------------------------------
// Producer: LN(chan) -> conv1x1 (MFMA bf16) in o-chunks of 64 -> depthwise 3x3
// One 8x8 patch per block; 10x10 halo recomputed. dst: [b][pi][pj][64px][128c]
// NCHUNK=2: x -> qd (chunks 0,1 = o 0..127 of dst0)
// NCHUNK=4: evt -> kd (chunks 0,1), vd (chunks 2,3)
// ---------------------------------------------------------------------------
#define PR_A     0        // ushort A[112][64] swizzled (14336)
#define PR_WB    14336    // ushort Wb[64][64] swizzled (8192)
#define PR_X     22528    // ushort xraw[64][105] (13440) / overlay: ushort pre[100][64] swz (12800)
#define PR_WDW   35968    // float swdw[576] (2304)
#define PR_LNW   38272    // float[64]
#define PR_LNB   38528    // float[64]
#define PR_MU    38784    // float[104]
#define PR_INV   39200    // float[104]
#define PR_SMEM  39616

template<int NCHUNK>
__global__ __launch_bounds__(512, 6)
void prod_kernel(const float* __restrict__ src, const float* __restrict__ wmat,
                 const float* __restrict__ wdw, const float* __restrict__ lnw,
                 const float* __restrict__ lnb,
                 unsigned short* __restrict__ dst0, unsigned short* __restrict__ dst1)
{
    __shared__ __align__(16) char smem[PR_SMEM];
    unsigned short* A    = (unsigned short*)(smem + PR_A);
    unsigned short* Wb   = (unsigned short*)(smem + PR_WB);
    unsigned short* xraw = (unsigned short*)(smem + PR_X);
    unsigned short* pre  = (unsigned short*)(smem + PR_X);   // overlays xraw (dead after A built)
    float* swdw = (float*)(smem + PR_WDW);
    float* slnw = (float*)(smem + PR_LNW);
    float* slnb = (float*)(smem + PR_LNB);
    float* smu  = (float*)(smem + PR_MU);
    float* sinv = (float*)(smem + PR_INV);

    const int tid = threadIdx.x;
    const int pj = blockIdx.x, pi = blockIdx.y, b = blockIdx.z;
    const int h0 = pi * 8, w0 = pj * 8;
    const int patchbase = ((b * 32 + pi) * 32 + pj) * 8192;   // ushorts

    if (tid < 64) { slnw[tid] = lnw[tid]; slnb[tid] = lnb[tid]; }
    for (int i = tid; i < 768; i += 512) A[6400 + i] = 0;     // zero pad rows 100..111
    // halo load (fp32 global -> bf16 LDS); OOB -> 0
    for (int i = tid; i < 6400; i += 512) {
        int c = i / 100, px = i - c * 100;
        int r = px / 10, cc = px - r * 10;
        int gh = h0 - 1 + r, gw = w0 - 1 + cc;
        float v = 0.f;
        if (gh >= 0 && gh < 256 && gw >= 0 && gw < 256)
            v = src[((b * 64 + c) * 256 + gh) * 256 + gw];
        xraw[c * 105 + px] = f2bf(v);
    }
    __syncthreads();

    // LN stats: 4 threads per pixel, quad shuffle-reduce
    if (tid < 400) {
        int px = tid >> 2, part = tid & 3;
        float s = 0.f, s2 = 0.f;
        #pragma unroll
        for (int cc = 0; cc < 16; ++cc) {
            float v = bfu(xraw[(part * 16 + cc) * 105 + px]);
            s += v; s2 += v * v;
        }
        s  += __shfl_xor(s, 1);  s  += __shfl_xor(s, 2);
        s2 += __shfl_xor(s2, 1); s2 += __shfl_xor(s2, 2);
        if (part == 0) {
            float mu = s * (1.f / 64.f);
            float var = s2 * (1.f / 64.f) - mu * mu;
            smu[px] = mu; sinv[px] = rsqrtf(var + 1e-5f);
        }
    }
    __syncthreads();

    // apply LN -> swizzled A (bf16); OOB pixels forced to 0 (SAME padding)
    for (int i = tid; i < 6400; i += 512) {
        int c = i / 100, px = i - c * 100;
        int r = px / 10, cc = px - r * 10;
        int gh = h0 - 1 + r, gw = w0 - 1 + cc;
        bool valid = (gh >= 0 && gh < 256 && gw >= 0 && gw < 256);
        float v = bfu(xraw[c * 105 + px]);
        float ln = (v - smu[px]) * sinv[px] * slnw[c] + slnb[c];
        A[px * 64 + (((c >> 3) ^ (px & 7)) << 3) + (c & 7)] =
            valid ? f2bf(ln) : (unsigned short)0;
    }
    __syncthreads();

    const int lane = tid & 63;
    const int l15 = lane & 15, l4 = lane >> 4;
    const int wave = tid >> 6;
    const int otile = wave & 3, mpart = wave >> 2;
    const int o_n = otile * 16 + l15;
    const int mt0 = mpart ? 4 : 0, mtn = mpart ? 3 : 4;

    #pragma unroll 1
    for (int ch = 0; ch < NCHUNK; ++ch) {
        // stage weight chunk (transposed+swizzled) + dw weights
        for (int i = tid; i < 4096; i += 512) {
            int oo = i >> 6, c = i & 63;
            Wb[oo * 64 + (((c >> 3) ^ (oo & 7)) << 3) + (c & 7)] =
                f2bf(wmat[(ch * 64 + oo) * 64 + c]);
        }
        if (tid < 512) { if (tid < 512) {} }
        for (int i = tid; i < 576; i += 512) swdw[i] = wdw[ch * 576 + i];
        __syncthreads();

        // MFMA: [112px x 64c] x [64c x 64o]
        f32x4 acc[4];
        #pragma unroll
        for (int mi = 0; mi < 4; ++mi) acc[mi] = (f32x4){0.f, 0.f, 0.f, 0.f};
        #pragma unroll
        for (int ks = 0; ks < 2; ++ks) {
            int cch = ks * 4 + l4;
            bf16x8 bfrag = *(const bf16x8*)&Wb[o_n * 64 + ((cch ^ (o_n & 7)) << 3)];
            #pragma unroll
            for (int mi = 0; mi < 4; ++mi) {
                if (mi < mtn) {
                    int px = (mt0 + mi) * 16 + l15;
                    bf16x8 afrag = *(const bf16x8*)&A[px * 64 + ((cch ^ (px & 7)) << 3)];
                    acc[mi] = __builtin_amdgcn_mfma_f32_16x16x32_bf16(afrag, bfrag, acc[mi], 0, 0, 0);
                }
            }
        }
        // C -> pre (bf16, swizzled)
        #pragma unroll
        for (int mi = 0; mi < 4; ++mi) {
            if (mi < mtn) {
                #pragma unroll
                for (int r = 0; r < 4; ++r) {
                    int px = (mt0 + mi) * 16 + l4 * 4 + r;
                    if (px < 100)
                        pre[px * 64 + (((o_n >> 3) ^ (px & 7)) << 3) + (o_n & 7)] = f2bf(acc[mi][r]);
                }
            }
        }
        __syncthreads();

        // depthwise 3x3 + store (this chunk's 64 channels)
        {
            const int opair = tid & 31, o = opair * 2;
            const int och = o >> 3, osub = o & 7;
            float wd0[9], wd1[9];
            #pragma unroll
            for (int t = 0; t < 9; ++t) { wd0[t] = swdw[o * 9 + t]; wd1[t] = swdw[o * 9 + 9 + t]; }
            unsigned short* dptr;
            int ooff;
            if (NCHUNK == 2) { dptr = dst0; ooff = ch * 64; }
            else             { dptr = (ch < 2) ? dst0 : dst1; ooff = (ch & 1) * 64; }
            #pragma unroll
            for (int it = 0; it < 4; ++it) {
                int px = (tid >> 5) + 16 * it;
                int pr = px >> 3, pc = px & 7;
                float a0 = 0.f, a1 = 0.f;
                #pragma unroll
                for (int dh = 0; dh < 3; ++dh)
                    #pragma unroll
                    for (int dwi = 0; dwi < 3; ++dwi) {
                        int hp = (pr + dh) * 10 + (pc + dwi);
                        unsigned int u = *(const unsigned int*)&pre[hp * 64 + ((och ^ (hp & 7)) << 3) + osub];
                        a0 += bflo(u) * wd0[dh * 3 + dwi];
                        a1 += bfhi(u) * wd1[dh * 3 + dwi];
                    }
                unsigned int outw = (unsigned int)f2bf(a0) | ((unsigned int)f2bf(a1) << 16);
                *(unsigned int*)&dptr[patchbase + px * 128 + ooff + o] = outw;
            }
        }
        __syncthreads();
    }
}

// ---------------------------------------------------------------------------
// Patch kernel: circular conv (regs) + LN(128) via wave shuffle + *v + proj MFMA
// 512 threads; thread = (pr = wave, cq = lane) owns channels {2cq, 2cq+1} x row pr
// ---------------------------------------------------------------------------
#define PK_Q    0       // sq bf16 [64px][128c] (16384) -> later sy (swizzled)
#define PK_K    16384   // sk (16384) -> later sv -> later sc f32 [64px][64o]
#define PK_WP   32768   // swp bf16 swizzled [64o][128c] (16384)
#define PK_LW   49152   // float[128]
#define PK_LB   49664   // float[128]
#define PK_SMEM 50176

__global__ __launch_bounds__(512, 6)
void patch_kernel(const unsigned short* __restrict__ qb,
                  const unsigned short* __restrict__ kb,
                  const unsigned short* __restrict__ vb,
                  const float* __restrict__ w_proj,
                  const float* __restrict__ lnw, const float* __restrict__ lnb,
                  float* __restrict__ out)
{
    __shared__ __align__(16) char smem[PK_SMEM];
    unsigned short* sq  = (unsigned short*)(smem + PK_Q);
    unsigned short* sk  = (unsigned short*)(smem + PK_K);
    unsigned short* sy  = sq;    // overlays sq (q dead after circular conv)
    unsigned short* sv  = sk;    // overlays sk (k dead after circular conv)
    float*          sc  = (float*)(smem + PK_K);   // overlays sv (dead after y-pack)
    unsigned short* swp = (unsigned short*)(smem + PK_WP);
    float* slw = (float*)(smem + PK_LW);
    float* slb = (float*)(smem + PK_LB);

    const int tid = threadIdx.x;
    const int tj = blockIdx.x, ti = blockIdx.y, b = blockIdx.z;
    const int h0 = ti * 8, w0 = tj * 8;
    const int pbase = ((b * 32 + ti) * 32 + tj) * 8192;   // ushorts

    // prefetch v to regs (T14 split: issue now, LDS-write after circular conv)
    u32x4 vreg0 = *(const u32x4*)&vb[pbase + tid * 16];
    u32x4 vreg1 = *(const u32x4*)&vb[pbase + tid * 16 + 8];

    if (tid < 128) { slw[tid] = lnw[tid]; slb[tid] = lnb[tid]; }
    // load q, k linear
    #pragma unroll
    for (int it = 0; it < 2; ++it) {
        int i = tid + it * 512;
        *(u32x4*)&sq[i * 8] = *(const u32x4*)&qb[pbase + i * 8];
        *(u32x4*)&sk[i * 8] = *(const u32x4*)&kb[pbase + i * 8];
    }
    // stage w_proj -> swp (bf16 swizzled)
    for (int i = tid; i < 8192; i += 512) {
        int o = i >> 7, c = i & 127;
        swp[o * 128 + (((c >> 3) ^ (o & 7)) << 3) + (c & 7)] = f2bf(w_proj[i]);
    }
    __syncthreads();

    const int pr = tid >> 6;       // wave index = patch row
    const int cq = tid & 63;       // channel pair
    const float lw0 = slw[2 * cq], lw1 = slw[2 * cq + 1];
    const float lb0 = slb[2 * cq], lb1 = slb[2 * cq + 1];

    // circular conv: acc[pc][ci] = out2[pr*8+pc][2cq+ci]
    float acc[8][2];
    #pragma unroll
    for (int pc = 0; pc < 8; ++pc) { acc[pc][0] = 0.f; acc[pc][1] = 0.f; }
    #pragma unroll
    for (int tr = 0; tr < 8; ++tr) {
        float qv[8][2];
        #pragma unroll
        for (int tc = 0; tc < 8; ++tc) {
            unsigned int u = *(const unsigned int*)&sq[(tr * 8 + tc) * 128 + cq * 2];
            qv[tc][0] = bflo(u); qv[tc][1] = bfhi(u);
        }
        int rrow = (pr - tr) & 7;
        float kv[8][2];
        #pragma unroll
        for (int j = 0; j < 8; ++j) {
            unsigned int u = *(const unsigned int*)&sk[(rrow * 8 + j) * 128 + cq * 2];
            kv[j][0] = bflo(u); kv[j][1] = bfhi(u);
        }
        #pragma unroll
        for (int tc = 0; tc < 8; ++tc)
            #pragma unroll
            for (int pc = 0; pc < 8; ++pc) {
                const int j = (pc - tc) & 7;
                acc[pc][0] += qv[tc][0] * kv[j][0];
                acc[pc][1] += qv[tc][1] * kv[j][1];
            }
    }
    __syncthreads();   // all sq/sk reads done

    // write prefetched v into sv (sk region)
    *(u32x4*)&sv[tid * 16]     = vreg0;
    *(u32x4*)&sv[tid * 16 + 8] = vreg1;

    // LN over 128 channels = full-wave shuffle reduce (lanes hold channel pairs)
    float mu[8], inv[8];
    #pragma unroll
    for (int pc = 0; pc < 8; ++pc) {
        float s  = acc[pc][0] + acc[pc][1];
        float s2 = acc[pc][0] * acc[pc][0] + acc[pc][1] * acc[pc][1];
        #pragma unroll
        for (int m = 1; m <= 32; m <<= 1) {
            s  += __shfl_xor(s, m);
            s2 += __shfl_xor(s2, m);
        }
        float m_ = s * (1.f / 128.f);
        mu[pc]  = m_;
        inv[pc] = rsqrtf(s2 * (1.f / 128.f) - m_ * m_ + 1e-5f);
    }
    __syncthreads();   // sv visible

    // y = LN(out2)*v -> sy (bf16 swizzled, overlays sq)
    #pragma unroll
    for (int pc = 0; pc < 8; ++pc) {
        int px = pr * 8 + pc;
        unsigned int uv = *(const unsigned int*)&sv[px * 128 + cq * 2];
        float y0 = ((acc[pc][0] - mu[pc]) * inv[pc] * lw0 + lb0) * bflo(uv);
        float y1 = ((acc[pc][1] - mu[pc]) * inv[pc] * lw1 + lb1) * bfhi(uv);
        unsigned int pk = (unsigned int)f2bf(y0) | ((unsigned int)f2bf(y1) << 16);
        *(unsigned int*)&sy[px * 128 + (((cq >> 2) ^ (px & 7)) << 3) + 2 * (cq & 3)] = pk;
    }
    __syncthreads();   // sy ready; sv reads done

    // proj MFMA: [64px x 128c] x [128c x 64o]; wave w: m-tile w>>1, o-tiles {2(w&1), 2(w&1)+1}
    {
        const int lane = tid & 63;
        const int l15 = lane & 15, l4 = lane >> 4;
        const int wave = tid >> 6;
        const int mt = wave >> 1;
        const int nt0 = 2 * (wave & 1);
        f32x4 pacc[2];
        pacc[0] = (f32x4){0.f, 0.f, 0.f, 0.f};
        pacc[1] = (f32x4){0.f, 0.f, 0.f, 0.f};
        const int px_a = mt * 16 + l15;
        #pragma unroll
        for (int ks = 0; ks < 4; ++ks) {
            int cch = ks * 4 + l4;
            bf16x8 af = *(const bf16x8*)&sy[px_a * 128 + ((cch ^ (px_a & 7)) << 3)];
            #pragma unroll
            for (int p2 = 0; p2 < 2; ++p2) {
                int o_n = (nt0 + p2) * 16 + l15;
                bf16x8 bfr = *(const bf16x8*)&swp[o_n * 128 + ((cch ^ (o_n & 7)) << 3)];
                pacc[p2] = __builtin_amdgcn_mfma_f32_16x16x32_bf16(af, bfr, pacc[p2], 0, 0, 0);
            }
        }
        // C -> sc (f32, overlays sk/sv region)
        #pragma unroll
        for (int p2 = 0; p2 < 2; ++p2)
            #pragma unroll
            for (int r = 0; r < 4; ++r) {
                int px = mt * 16 + l4 * 4 + r;
                int o = (nt0 + p2) * 16 + l15;
                sc[px * 64 + o] = pacc[p2][r];
            }
    }
    __syncthreads();

    // store: thread = (o, r), 8 contiguous floats per row
    {
        const int o = tid & 63, r = tid >> 6;
        float v0[4], v1[4];
        #pragma unroll
        for (int j = 0; j < 4; ++j) {
            v0[j] = sc[(r * 8 + j) * 64 + o];
            v1[j] = sc[(r * 8 + 4 + j) * 64 + o];
        }
        int obase = ((b * 64 + o) * 256 + h0 + r) * 256 + w0;
        *(f32x4*)&out[obase]     = (f32x4){v0[0], v0[1], v0[2], v0[3]};
        *(f32x4*)&out[obase + 4] = (f32x4){v1[0], v1[1], v1[2], v1[3]};
    }
}

extern "C" void kernel_launch(void* const* d_in, const int* in_sizes, int n_in,
                              void* d_out, int out_size, void* d_ws, size_t ws_size,
                              hipStream_t stream) {
    (void)in_sizes; (void)n_in; (void)out_size; (void)ws_size;
    const float* x        = (const float*)d_in[0];
    const float* evt      = (const float*)d_in[1];
    const float* w_q      = (const float*)d_in[2];
    const float* w_kv     = (const float*)d_in[3];
    const float* w_qdw    = (const float*)d_in[4];
    const float* w_kvdw   = (const float*)d_in[5];
    const float* w_proj   = (const float*)d_in[6];
    const float* ln_img_w = (const float*)d_in[7];
    const float* ln_img_b = (const float*)d_in[8];
    const float* ln_evt_w = (const float*)d_in[9];
    const float* ln_evt_b = (const float*)d_in[10];
    const float* ln_out_w = (const float*)d_in[11];
    const float* ln_out_b = (const float*)d_in[12];
    float* out = (float*)d_out;

    // workspace: q/k/v post-dw, each [4][32][32][64px][128c] bf16 = 64 MiB (192 MiB total)
    unsigned short* qd = (unsigned short*)d_ws;
    unsigned short* kd = qd + (size_t)4 * 32 * 32 * 8192;
    unsigned short* vd = kd + (size_t)4 * 32 * 32 * 8192;

    dim3 grid(32, 32, 4), blk(512);
    prod_kernel<2><<<grid, blk, 0, stream>>>(x,   w_q,  w_qdw,  ln_img_w, ln_img_b, qd, qd);
    prod_kernel<4><<<grid, blk, 0, stream>>>(evt, w_kv, w_kvdw, ln_evt_w, ln_evt_b, kd, vd);
    patch_kernel<<<grid, blk, 0, stream>>>(qd, kd, vd, w_proj, ln_out_w, ln_out_b, out);
}

// Round 4
// 379.125 us; speedup vs baseline: 1.7470x; 1.7470x over previous
//
#include <hip/hip_runtime.h>

typedef __attribute__((ext_vector_type(8))) short bf16x8;
typedef __attribute__((ext_vector_type(4))) float f32x4;
typedef __attribute__((ext_vector_type(4))) unsigned int u32x4;
typedef __attribute__((ext_vector_type(2))) unsigned int u32x2;

__device__ __forceinline__ unsigned short f2bf(float f) {
    union { float f; unsigned int u; } v; v.f = f;
    return (unsigned short)((v.u + 0x7fffu + ((v.u >> 16) & 1u)) >> 16);
}
__device__ __forceinline__ float bflo(unsigned int u) {
    union { unsigned int u; float f; } v; v.u = u << 16; return v.f;
}
__device__ __forceinline__ float bfhi(unsigned int u) {
    union { unsigned int u; float f; } v; v.u = u & 0xffff0000u; return v.f;
}

// ---------------------------------------------------------------------------
// K1: channel LayerNorm, NCHW fp32 -> NHWC bf16. One pixel per thread.
// ---------------------------------------------------------------------------
__global__ __launch_bounds__(256, 4)
void ln_kernel(const float* __restrict__ x, const float* __restrict__ evt,
               const float* __restrict__ lwx, const float* __restrict__ lbx,
               const float* __restrict__ lwe, const float* __restrict__ lbe,
               unsigned short* __restrict__ xo, unsigned short* __restrict__ eo)
{
    const int z = blockIdx.z;
    const float* src = z ? evt : x;
    const float* lw  = z ? lwe : lwx;
    const float* lb  = z ? lbe : lbx;
    unsigned short* dst = z ? eo : xo;
    const int px = blockIdx.x * 256 + threadIdx.x;   // [0, 4*65536)
    const int b = px >> 16, hw = px & 65535;
    const float* sp = src + (size_t)b * 64 * 65536 + hw;

    float v[64];
    float s = 0.f, s2 = 0.f;
    #pragma unroll
    for (int c = 0; c < 64; ++c) {
        float t = sp[(size_t)c * 65536];
        v[c] = t; s += t; s2 += t * t;
    }
    float mu  = s * (1.f / 64.f);
    float inv = rsqrtf(s2 * (1.f / 64.f) - mu * mu + 1e-5f);

    unsigned short* dp = dst + (size_t)px * 64;
    #pragma unroll
    for (int j = 0; j < 8; ++j) {
        u32x4 w;
        #pragma unroll
        for (int q = 0; q < 4; ++q) {
            int c = j * 8 + q * 2;
            float a0 = (v[c]     - mu) * inv * lw[c]     + lb[c];
            float a1 = (v[c + 1] - mu) * inv * lw[c + 1] + lb[c + 1];
            w[q] = (unsigned int)f2bf(a0) | ((unsigned int)f2bf(a1) << 16);
        }
        *(u32x4*)&dp[j * 8] = w;
    }
}

// ---------------------------------------------------------------------------
// K2: producer: conv1x1 (MFMA bf16, 128 out) + depthwise 3x3.
// Input NHWC bf16 (LN'd); one 8x8 patch per block, 10x10 halo recomputed.
// dst: [b][pi][pj][64px][128c] bf16
// LDS: A[112][64] swz (14336) + Wb[128][64] swz (16384); pre[100][128] swz
//      (25600) OVERLAYS A+Wb after MFMA-read sync. + swdw f32 (4608).
// ---------------------------------------------------------------------------
#define PR_WB    14336
#define PR_WDW   30720
#define PR_SMEM  35328

__global__ __launch_bounds__(512, 6)
void prod_kernel(const unsigned short* __restrict__ src,
                 const float* __restrict__ wmat, const float* __restrict__ wdw,
                 unsigned short* __restrict__ dst)
{
    __shared__ __align__(16) char smem[PR_SMEM];
    unsigned short* A   = (unsigned short*)(smem);
    unsigned short* Wb  = (unsigned short*)(smem + PR_WB);
    unsigned short* pre = (unsigned short*)(smem);          // overlays A+Wb
    float* swdw = (float*)(smem + PR_WDW);

    const int tid = threadIdx.x;
    const int pj = blockIdx.x, pi = blockIdx.y, b = blockIdx.z;
    const int h0 = pi * 8, w0 = pj * 8;

    // stage Wb: [128o][64c] fp32 -> bf16 swizzled (vectorized)
    #pragma unroll
    for (int it = 0; it < 4; ++it) {
        int i = tid + it * 512;        // 2048 tasks
        int o = i >> 4, c4 = i & 15;
        f32x4 wv = *(const f32x4*)&wmat[o * 64 + c4 * 4];
        unsigned int lo = (unsigned int)f2bf(wv[0]) | ((unsigned int)f2bf(wv[1]) << 16);
        unsigned int hi = (unsigned int)f2bf(wv[2]) | ((unsigned int)f2bf(wv[3]) << 16);
        u32x2 pk = {lo, hi};
        *(u32x2*)&Wb[o * 64 + (((c4 >> 1) ^ (o & 7)) << 3) + (c4 & 1) * 4] = pk;
    }
    for (int i = tid; i < 1152; i += 512) swdw[i] = wdw[i];
    for (int i = tid; i < 768; i += 512) A[6400 + i] = 0;   // zero rows 100..111
    // stage A: 100 halo px x 8 octs, 16B coalesced loads; OOB -> 0
    #pragma unroll
    for (int it = 0; it < 2; ++it) {
        int i = tid + it * 512;
        if (i < 800) {
            int px = i >> 3, oct = i & 7;
            int r = px / 10, cc = px - r * 10;
            int gh = h0 - 1 + r, gw = w0 - 1 + cc;
            u32x4 val = {0u, 0u, 0u, 0u};
            if (gh >= 0 && gh < 256 && gw >= 0 && gw < 256)
                val = *(const u32x4*)&src[((size_t)(b * 65536 + gh * 256 + gw)) * 64 + oct * 8];
            *(u32x4*)&A[px * 64 + ((oct ^ (px & 7)) << 3)] = val;
        }
    }
    __syncthreads();

    // MFMA: [112px x 64c] x [64c x 128o]; wave owns o-tile (tid>>6)
    const int lane = tid & 63;
    const int l15 = lane & 15, l4 = lane >> 4;
    const int o_n = (tid >> 6) * 16 + l15;
    f32x4 acc[7];
    #pragma unroll
    for (int mt = 0; mt < 7; ++mt) acc[mt] = (f32x4){0.f, 0.f, 0.f, 0.f};
    #pragma unroll
    for (int ks = 0; ks < 2; ++ks) {
        int cch = ks * 4 + l4;
        bf16x8 bfrag = *(const bf16x8*)&Wb[o_n * 64 + ((cch ^ (o_n & 7)) << 3)];
        #pragma unroll
        for (int mt = 0; mt < 7; ++mt) {
            int px = mt * 16 + l15;
            bf16x8 afrag = *(const bf16x8*)&A[px * 64 + ((cch ^ (px & 7)) << 3)];
            acc[mt] = __builtin_amdgcn_mfma_f32_16x16x32_bf16(afrag, bfrag, acc[mt], 0, 0, 0);
        }
    }
    __syncthreads();   // all A/Wb fragment reads done -> pre may overlay

    #pragma unroll
    for (int mt = 0; mt < 7; ++mt)
        #pragma unroll
        for (int r = 0; r < 4; ++r) {
            int px = mt * 16 + l4 * 4 + r;
            if (px < 100)
                pre[px * 128 + (((o_n >> 3) ^ (px & 7)) << 3) + (o_n & 7)] = f2bf(acc[mt][r]);
        }
    __syncthreads();

    // depthwise 3x3 + store; thread = (o-pair = tid&63, px = (tid>>6)+8i)
    {
        const int o = (tid & 63) * 2;
        const int och = o >> 3, osub = o & 7;
        float wd0[9], wd1[9];
        #pragma unroll
        for (int t = 0; t < 9; ++t) { wd0[t] = swdw[o * 9 + t]; wd1[t] = swdw[o * 9 + 9 + t]; }
        const size_t patchbase = ((size_t)(b * 32 + pi) * 32 + pj) * 8192;
        #pragma unroll
        for (int i = 0; i < 8; ++i) {
            int px = (tid >> 6) + 8 * i;
            int pr = px >> 3, pc = px & 7;
            float a0 = 0.f, a1 = 0.f;
            #pragma unroll
            for (int dh = 0; dh < 3; ++dh)
                #pragma unroll
                for (int dwi = 0; dwi < 3; ++dwi) {
                    int hp = (pr + dh) * 10 + (pc + dwi);
                    unsigned int u = *(const unsigned int*)&pre[hp * 128 + ((och ^ (hp & 7)) << 3) + osub];
                    a0 += bflo(u) * wd0[dh * 3 + dwi];
                    a1 += bfhi(u) * wd1[dh * 3 + dwi];
                }
            unsigned int outw = (unsigned int)f2bf(a0) | ((unsigned int)f2bf(a1) << 16);
            *(unsigned int*)&dst[patchbase + px * 128 + o] = outw;
        }
    }
}

// ---------------------------------------------------------------------------
// K3: patch kernel (R3, validated): circular conv (regs) + LN(128) shuffle +
// *v + proj MFMA. 512 threads; thread = (pr = wave, cq = lane).
// ---------------------------------------------------------------------------
#define PK_Q    0
#define PK_K    16384
#define PK_WP   32768
#define PK_LW   49152
#define PK_LB   49664
#define PK_SMEM 50176

__global__ __launch_bounds__(512, 6)
void patch_kernel(const unsigned short* __restrict__ qb,
                  const unsigned short* __restrict__ kb,
                  const unsigned short* __restrict__ vb,
                  const float* __restrict__ w_proj,
                  const float* __restrict__ lnw, const float* __restrict__ lnb,
                  float* __restrict__ out)
{
    __shared__ __align__(16) char smem[PK_SMEM];
    unsigned short* sq  = (unsigned short*)(smem + PK_Q);
    unsigned short* sk  = (unsigned short*)(smem + PK_K);
    unsigned short* sy  = sq;
    unsigned short* sv  = sk;
    float*          sc  = (float*)(smem + PK_K);
    unsigned short* swp = (unsigned short*)(smem + PK_WP);
    float* slw = (float*)(smem + PK_LW);
    float* slb = (float*)(smem + PK_LB);

    const int tid = threadIdx.x;
    const int tj = blockIdx.x, ti = blockIdx.y, b = blockIdx.z;
    const int h0 = ti * 8, w0 = tj * 8;
    const size_t pbase = ((size_t)(b * 32 + ti) * 32 + tj) * 8192;

    u32x4 vreg0 = *(const u32x4*)&vb[pbase + tid * 16];
    u32x4 vreg1 = *(const u32x4*)&vb[pbase + tid * 16 + 8];

    if (tid < 128) { slw[tid] = lnw[tid]; slb[tid] = lnb[tid]; }
    #pragma unroll
    for (int it = 0; it < 2; ++it) {
        int i = tid + it * 512;
        *(u32x4*)&sq[i * 8] = *(const u32x4*)&qb[pbase + i * 8];
        *(u32x4*)&sk[i * 8] = *(const u32x4*)&kb[pbase + i * 8];
    }
    // stage w_proj -> swp (bf16 swizzled), vectorized float4
    #pragma unroll
    for (int it = 0; it < 4; ++it) {
        int i = tid + it * 512;        // 2048 tasks
        int o = i >> 5, c4 = i & 31;
        f32x4 wv = *(const f32x4*)&w_proj[o * 128 + c4 * 4];
        unsigned int lo = (unsigned int)f2bf(wv[0]) | ((unsigned int)f2bf(wv[1]) << 16);
        unsigned int hi = (unsigned int)f2bf(wv[2]) | ((unsigned int)f2bf(wv[3]) << 16);
        u32x2 pk = {lo, hi};
        *(u32x2*)&swp[o * 128 + (((c4 >> 1) ^ (o & 7)) << 3) + (c4 & 1) * 4] = pk;
    }
    __syncthreads();

    const int pr = tid >> 6;
    const int cq = tid & 63;
    const float lw0 = slw[2 * cq], lw1 = slw[2 * cq + 1];
    const float lb0 = slb[2 * cq], lb1 = slb[2 * cq + 1];

    float acc[8][2];
    #pragma unroll
    for (int pc = 0; pc < 8; ++pc) { acc[pc][0] = 0.f; acc[pc][1] = 0.f; }
    #pragma unroll
    for (int tr = 0; tr < 8; ++tr) {
        float qv[8][2];
        #pragma unroll
        for (int tc = 0; tc < 8; ++tc) {
            unsigned int u = *(const unsigned int*)&sq[(tr * 8 + tc) * 128 + cq * 2];
            qv[tc][0] = bflo(u); qv[tc][1] = bfhi(u);
        }
        int rrow = (pr - tr) & 7;
        float kv[8][2];
        #pragma unroll
        for (int j = 0; j < 8; ++j) {
            unsigned int u = *(const unsigned int*)&sk[(rrow * 8 + j) * 128 + cq * 2];
            kv[j][0] = bflo(u); kv[j][1] = bfhi(u);
        }
        #pragma unroll
        for (int tc = 0; tc < 8; ++tc)
            #pragma unroll
            for (int pc = 0; pc < 8; ++pc) {
                const int j = (pc - tc) & 7;
                acc[pc][0] += qv[tc][0] * kv[j][0];
                acc[pc][1] += qv[tc][1] * kv[j][1];
            }
    }
    __syncthreads();

    *(u32x4*)&sv[tid * 16]     = vreg0;
    *(u32x4*)&sv[tid * 16 + 8] = vreg1;

    float mu[8], inv[8];
    #pragma unroll
    for (int pc = 0; pc < 8; ++pc) {
        float s  = acc[pc][0] + acc[pc][1];
        float s2 = acc[pc][0] * acc[pc][0] + acc[pc][1] * acc[pc][1];
        #pragma unroll
        for (int m = 1; m <= 32; m <<= 1) {
            s  += __shfl_xor(s, m);
            s2 += __shfl_xor(s2, m);
        }
        float m_ = s * (1.f / 128.f);
        mu[pc]  = m_;
        inv[pc] = rsqrtf(s2 * (1.f / 128.f) - m_ * m_ + 1e-5f);
    }
    __syncthreads();

    #pragma unroll
    for (int pc = 0; pc < 8; ++pc) {
        int px = pr * 8 + pc;
        unsigned int uv = *(const unsigned int*)&sv[px * 128 + cq * 2];
        float y0 = ((acc[pc][0] - mu[pc]) * inv[pc] * lw0 + lb0) * bflo(uv);
        float y1 = ((acc[pc][1] - mu[pc]) * inv[pc] * lw1 + lb1) * bfhi(uv);
        unsigned int pk = (unsigned int)f2bf(y0) | ((unsigned int)f2bf(y1) << 16);
        *(unsigned int*)&sy[px * 128 + (((cq >> 2) ^ (px & 7)) << 3) + 2 * (cq & 3)] = pk;
    }
    __syncthreads();

    {
        const int lane = tid & 63;
        const int l15 = lane & 15, l4 = lane >> 4;
        const int wave = tid >> 6;
        const int mt = wave >> 1;
        const int nt0 = 2 * (wave & 1);
        f32x4 pacc[2];
        pacc[0] = (f32x4){0.f, 0.f, 0.f, 0.f};
        pacc[1] = (f32x4){0.f, 0.f, 0.f, 0.f};
        const int px_a = mt * 16 + l15;
        #pragma unroll
        for (int ks = 0; ks < 4; ++ks) {
            int cch = ks * 4 + l4;
            bf16x8 af = *(const bf16x8*)&sy[px_a * 128 + ((cch ^ (px_a & 7)) << 3)];
            #pragma unroll
            for (int p2 = 0; p2 < 2; ++p2) {
                int o_n = (nt0 + p2) * 16 + l15;
                bf16x8 bfr = *(const bf16x8*)&swp[o_n * 128 + ((cch ^ (o_n & 7)) << 3)];
                pacc[p2] = __builtin_amdgcn_mfma_f32_16x16x32_bf16(af, bfr, pacc[p2], 0, 0, 0);
            }
        }
        #pragma unroll
        for (int p2 = 0; p2 < 2; ++p2)
            #pragma unroll
            for (int r = 0; r < 4; ++r) {
                int px = mt * 16 + l4 * 4 + r;
                int o = (nt0 + p2) * 16 + l15;
                sc[px * 64 + o] = pacc[p2][r];
            }
    }
    __syncthreads();

    {
        const int o = tid & 63, r = tid >> 6;
        float v0[4], v1[4];
        #pragma unroll
        for (int j = 0; j < 4; ++j) {
            v0[j] = sc[(r * 8 + j) * 64 + o];
            v1[j] = sc[(r * 8 + 4 + j) * 64 + o];
        }
        int obase = ((b * 64 + o) * 256 + h0 + r) * 256 + w0;
        *(f32x4*)&out[obase]     = (f32x4){v0[0], v0[1], v0[2], v0[3]};
        *(f32x4*)&out[obase + 4] = (f32x4){v1[0], v1[1], v1[2], v1[3]};
    }
}

extern "C" void kernel_launch(void* const* d_in, const int* in_sizes, int n_in,
                              void* d_out, int out_size, void* d_ws, size_t ws_size,
                              hipStream_t stream) {
    (void)in_sizes; (void)n_in; (void)out_size; (void)ws_size;
    const float* x        = (const float*)d_in[0];
    const float* evt      = (const float*)d_in[1];
    const float* w_q      = (const float*)d_in[2];
    const float* w_kv     = (const float*)d_in[3];
    const float* w_qdw    = (const float*)d_in[4];
    const float* w_kvdw   = (const float*)d_in[5];
    const float* w_proj   = (const float*)d_in[6];
    const float* ln_img_w = (const float*)d_in[7];
    const float* ln_img_b = (const float*)d_in[8];
    const float* ln_evt_w = (const float*)d_in[9];
    const float* ln_evt_b = (const float*)d_in[10];
    const float* ln_out_w = (const float*)d_in[11];
    const float* ln_out_b = (const float*)d_in[12];
    float* out = (float*)d_out;

    // workspace (ushort units). vd overlays xln (xln dead after prod-q).
    const size_t NPATCH = (size_t)4 * 32 * 32 * 8192;   // 33.5M ushorts = 64 MiB
    const size_t NLN    = (size_t)4 * 65536 * 64;       // 16.7M ushorts = 32 MiB
    unsigned short* qd  = (unsigned short*)d_ws;
    unsigned short* kd  = qd + NPATCH;
    unsigned short* eln = kd + NPATCH;
    unsigned short* xln = eln + NLN;
    unsigned short* vd  = xln;                           // overlay

    dim3 lgrid(1024, 1, 2), lblk(256);
    ln_kernel<<<lgrid, lblk, 0, stream>>>(x, evt, ln_img_w, ln_img_b,
                                          ln_evt_w, ln_evt_b, xln, eln);
    dim3 grid(32, 32, 4), blk(512);
    prod_kernel<<<grid, blk, 0, stream>>>(xln, w_q,            w_qdw,           qd);
    prod_kernel<<<grid, blk, 0, stream>>>(eln, w_kv,           w_kvdw,          kd);
    prod_kernel<<<grid, blk, 0, stream>>>(eln, w_kv + 128*64,  w_kvdw + 128*9,  vd);
    patch_kernel<<<grid, blk, 0, stream>>>(qd, kd, vd, w_proj, ln_out_w, ln_out_b, out);
}

// Round 5
// 283.976 us; speedup vs baseline: 2.3324x; 1.3351x over previous
//
#include <hip/hip_runtime.h>

typedef __attribute__((ext_vector_type(8))) short bf16x8;
typedef __attribute__((ext_vector_type(4))) float f32x4;
typedef __attribute__((ext_vector_type(2))) float f32x2;
typedef __attribute__((ext_vector_type(4))) unsigned int u32x4;
typedef __attribute__((ext_vector_type(2))) unsigned int u32x2;

__device__ __forceinline__ unsigned short f2bf(float f) {
    union { float f; unsigned int u; } v; v.f = f;
    return (unsigned short)((v.u + 0x7fffu + ((v.u >> 16) & 1u)) >> 16);
}
__device__ __forceinline__ float bflo(unsigned int u) {
    union { unsigned int u; float f; } v; v.u = u << 16; return v.f;
}
__device__ __forceinline__ float bfhi(unsigned int u) {
    union { unsigned int u; float f; } v; v.u = u & 0xffff0000u; return v.f;
}
__device__ __forceinline__ f32x2 bfpair(unsigned int u) {
    union { unsigned int u; float f; } lo, hi;
    lo.u = u << 16; hi.u = u & 0xffff0000u;
    return (f32x2){lo.f, hi.f};
}

// Canonical gfx9 64-lane all-sum via DPP (VALU pipe, not LDS pipe).
// s_nop 1 between VALU-write and DPP-read (2 wait states, gfx9 hazard).
__device__ __forceinline__ float wred_allsum(float x) {
    asm volatile(
        "s_nop 1\n\t"
        "v_add_f32_dpp %0, %0, %0 row_shr:1 bound_ctrl:0\n\t"
        "s_nop 1\n\t"
        "v_add_f32_dpp %0, %0, %0 row_shr:2 bound_ctrl:0\n\t"
        "s_nop 1\n\t"
        "v_add_f32_dpp %0, %0, %0 row_shr:4 bound_ctrl:0\n\t"
        "s_nop 1\n\t"
        "v_add_f32_dpp %0, %0, %0 row_shr:8 bound_ctrl:0\n\t"
        "s_nop 1\n\t"
        "v_add_f32_dpp %0, %0, %0 row_bcast:15 row_mask:0xa bound_ctrl:0\n\t"
        "s_nop 1\n\t"
        "v_add_f32_dpp %0, %0, %0 row_bcast:31 row_mask:0xc bound_ctrl:0\n\t"
        "s_nop 1"
        : "+v"(x));
    return __builtin_bit_cast(float, __builtin_amdgcn_readlane(__builtin_bit_cast(int, x), 63));
}

// ---------------------------------------------------------------------------
// K1: channel LayerNorm, NCHW fp32 -> NHWC bf16. One pixel per thread.
// ---------------------------------------------------------------------------
__global__ __launch_bounds__(256, 4)
void ln_kernel(const float* __restrict__ x, const float* __restrict__ evt,
               const float* __restrict__ lwx, const float* __restrict__ lbx,
               const float* __restrict__ lwe, const float* __restrict__ lbe,
               unsigned short* __restrict__ xo, unsigned short* __restrict__ eo)
{
    const int z = blockIdx.z;
    const float* src = z ? evt : x;
    const float* lw  = z ? lwe : lwx;
    const float* lb  = z ? lbe : lbx;
    unsigned short* dst = z ? eo : xo;
    const int px = blockIdx.x * 256 + threadIdx.x;
    const int b = px >> 16, hw = px & 65535;
    const float* sp = src + (size_t)b * 64 * 65536 + hw;

    float v[64];
    float s = 0.f, s2 = 0.f;
    #pragma unroll
    for (int c = 0; c < 64; ++c) {
        float t = sp[(size_t)c * 65536];
        v[c] = t; s += t; s2 += t * t;
    }
    float mu  = s * (1.f / 64.f);
    float inv = rsqrtf(s2 * (1.f / 64.f) - mu * mu + 1e-5f);

    unsigned short* dp = dst + (size_t)px * 64;
    #pragma unroll
    for (int j = 0; j < 8; ++j) {
        u32x4 w;
        #pragma unroll
        for (int q = 0; q < 4; ++q) {
            int c = j * 8 + q * 2;
            float a0 = (v[c]     - mu) * inv * lw[c]     + lb[c];
            float a1 = (v[c + 1] - mu) * inv * lw[c + 1] + lb[c + 1];
            w[q] = (unsigned int)f2bf(a0) | ((unsigned int)f2bf(a1) << 16);
        }
        *(u32x4*)&dp[j * 8] = w;
    }
}

// ---------------------------------------------------------------------------
// K2: producer: conv1x1 (MFMA bf16, 128 out) + depthwise 3x3 (ring + pk_fma).
// ---------------------------------------------------------------------------
#define PR_WB    14336
#define PR_WDW   30720
#define PR_SMEM  35328

__global__ __launch_bounds__(512, 8)
void prod_kernel(const unsigned short* __restrict__ src,
                 const float* __restrict__ wmat, const float* __restrict__ wdw,
                 unsigned short* __restrict__ dst)
{
    __shared__ __align__(16) char smem[PR_SMEM];
    unsigned short* A   = (unsigned short*)(smem);
    unsigned short* Wb  = (unsigned short*)(smem + PR_WB);
    unsigned short* pre = (unsigned short*)(smem);          // overlays A+Wb
    float* swdw = (float*)(smem + PR_WDW);

    const int tid = threadIdx.x;
    const int pj = blockIdx.x, pi = blockIdx.y, b = blockIdx.z;
    const int h0 = pi * 8, w0 = pj * 8;

    #pragma unroll
    for (int it = 0; it < 4; ++it) {
        int i = tid + it * 512;
        int o = i >> 4, c4 = i & 15;
        f32x4 wv = *(const f32x4*)&wmat[o * 64 + c4 * 4];
        unsigned int lo = (unsigned int)f2bf(wv[0]) | ((unsigned int)f2bf(wv[1]) << 16);
        unsigned int hi = (unsigned int)f2bf(wv[2]) | ((unsigned int)f2bf(wv[3]) << 16);
        u32x2 pk = {lo, hi};
        *(u32x2*)&Wb[o * 64 + (((c4 >> 1) ^ (o & 7)) << 3) + (c4 & 1) * 4] = pk;
    }
    for (int i = tid; i < 1152; i += 512) swdw[i] = wdw[i];
    for (int i = tid; i < 768; i += 512) A[6400 + i] = 0;
    #pragma unroll
    for (int it = 0; it < 2; ++it) {
        int i = tid + it * 512;
        if (i < 800) {
            int px = i >> 3, oct = i & 7;
            int r = px / 10, cc = px - r * 10;
            int gh = h0 - 1 + r, gw = w0 - 1 + cc;
            u32x4 val = {0u, 0u, 0u, 0u};
            if (gh >= 0 && gh < 256 && gw >= 0 && gw < 256)
                val = *(const u32x4*)&src[((size_t)(b * 65536 + gh * 256 + gw)) * 64 + oct * 8];
            *(u32x4*)&A[px * 64 + ((oct ^ (px & 7)) << 3)] = val;
        }
    }
    __syncthreads();

    // MFMA: [112px x 64c] x [64c x 128o]
    const int lane = tid & 63;
    const int l15 = lane & 15, l4 = lane >> 4;
    const int o_n = (tid >> 6) * 16 + l15;
    f32x4 acc[7];
    #pragma unroll
    for (int mt = 0; mt < 7; ++mt) acc[mt] = (f32x4){0.f, 0.f, 0.f, 0.f};
    #pragma unroll
    for (int ks = 0; ks < 2; ++ks) {
        int cch = ks * 4 + l4;
        bf16x8 bfrag = *(const bf16x8*)&Wb[o_n * 64 + ((cch ^ (o_n & 7)) << 3)];
        #pragma unroll
        for (int mt = 0; mt < 7; ++mt) {
            int px = mt * 16 + l15;
            bf16x8 afrag = *(const bf16x8*)&A[px * 64 + ((cch ^ (px & 7)) << 3)];
            acc[mt] = __builtin_amdgcn_mfma_f32_16x16x32_bf16(afrag, bfrag, acc[mt], 0, 0, 0);
        }
    }
    __syncthreads();   // A/Wb reads done -> pre may overlay

    #pragma unroll
    for (int mt = 0; mt < 7; ++mt)
        #pragma unroll
        for (int r = 0; r < 4; ++r) {
            int px = mt * 16 + l4 * 4 + r;
            if (px < 100)
                pre[px * 128 + (((o_n >> 3) ^ (px & 7)) << 3) + (o_n & 7)] = f2bf(acc[mt][r]);
        }
    __syncthreads();

    // depthwise 3x3: thread = (o-pair, pixel column); 10-row ring, pk_fma
    {
        const int o = (tid & 63) * 2;
        const int och = o >> 3, osub = o & 7;
        const int pc = tid >> 6;
        f32x2 wdp[9];
        #pragma unroll
        for (int t = 0; t < 9; ++t)
            wdp[t] = (f32x2){swdw[o * 9 + t], swdw[o * 9 + 9 + t]};
        const size_t patchbase = ((size_t)(b * 32 + pi) * 32 + pj) * 8192;

        f32x2 ra[3], rb[3], rc[3];
        #define LOADROW(dstv, rr)                                                        \
            {                                                                            \
                _Pragma("unroll")                                                        \
                for (int d = 0; d < 3; ++d) {                                            \
                    int hp = (rr) * 10 + pc + d;                                         \
                    unsigned int u = *(const unsigned int*)                              \
                        &pre[hp * 128 + ((och ^ (hp & 7)) << 3) + osub];                 \
                    dstv[d] = bfpair(u);                                                 \
                }                                                                        \
            }
        LOADROW(ra, 0)
        LOADROW(rb, 1)
        #pragma unroll
        for (int r = 2; r < 10; ++r) {
            LOADROW(rc, r)
            f32x2 s = ra[0] * wdp[0];
            s += ra[1] * wdp[1]; s += ra[2] * wdp[2];
            s += rb[0] * wdp[3]; s += rb[1] * wdp[4]; s += rb[2] * wdp[5];
            s += rc[0] * wdp[6]; s += rc[1] * wdp[7]; s += rc[2] * wdp[8];
            int px = (r - 2) * 8 + pc;
            unsigned int outw = (unsigned int)f2bf(s.x) | ((unsigned int)f2bf(s.y) << 16);
            *(unsigned int*)&dst[patchbase + px * 128 + o] = outw;
            #pragma unroll
            for (int d = 0; d < 3; ++d) { ra[d] = rb[d]; rb[d] = rc[d]; }
        }
        #undef LOADROW
    }
}

// ---------------------------------------------------------------------------
// K3: patch kernel: circular conv (pk_fma) + LN(128) via DPP + *v + proj MFMA
// ---------------------------------------------------------------------------
#define PK_Q    0
#define PK_K    16384
#define PK_WP   32768
#define PK_LW   49152
#define PK_LB   49664
#define PK_SMEM 50176

__global__ __launch_bounds__(512, 6)
void patch_kernel(const unsigned short* __restrict__ qb,
                  const unsigned short* __restrict__ kb,
                  const unsigned short* __restrict__ vb,
                  const float* __restrict__ w_proj,
                  const float* __restrict__ lnw, const float* __restrict__ lnb,
                  float* __restrict__ out)
{
    __shared__ __align__(16) char smem[PK_SMEM];
    unsigned short* sq  = (unsigned short*)(smem + PK_Q);
    unsigned short* sk  = (unsigned short*)(smem + PK_K);
    unsigned short* sy  = sq;
    unsigned short* sv  = sk;
    float*          sc  = (float*)(smem + PK_K);
    unsigned short* swp = (unsigned short*)(smem + PK_WP);
    float* slw = (float*)(smem + PK_LW);
    float* slb = (float*)(smem + PK_LB);

    const int tid = threadIdx.x;
    const int tj = blockIdx.x, ti = blockIdx.y, b = blockIdx.z;
    const int h0 = ti * 8, w0 = tj * 8;
    const size_t pbase = ((size_t)(b * 32 + ti) * 32 + tj) * 8192;

    u32x4 vreg0 = *(const u32x4*)&vb[pbase + tid * 16];
    u32x4 vreg1 = *(const u32x4*)&vb[pbase + tid * 16 + 8];

    if (tid < 128) { slw[tid] = lnw[tid]; slb[tid] = lnb[tid]; }
    #pragma unroll
    for (int it = 0; it < 2; ++it) {
        int i = tid + it * 512;
        *(u32x4*)&sq[i * 8] = *(const u32x4*)&qb[pbase + i * 8];
        *(u32x4*)&sk[i * 8] = *(const u32x4*)&kb[pbase + i * 8];
    }
    #pragma unroll
    for (int it = 0; it < 4; ++it) {
        int i = tid + it * 512;
        int o = i >> 5, c4 = i & 31;
        f32x4 wv = *(const f32x4*)&w_proj[o * 128 + c4 * 4];
        unsigned int lo = (unsigned int)f2bf(wv[0]) | ((unsigned int)f2bf(wv[1]) << 16);
        unsigned int hi = (unsigned int)f2bf(wv[2]) | ((unsigned int)f2bf(wv[3]) << 16);
        u32x2 pk = {lo, hi};
        *(u32x2*)&swp[o * 128 + (((c4 >> 1) ^ (o & 7)) << 3) + (c4 & 1) * 4] = pk;
    }
    __syncthreads();

    const int pr = tid >> 6;
    const int cq = tid & 63;
    const float lw0 = slw[2 * cq], lw1 = slw[2 * cq + 1];
    const float lb0 = slb[2 * cq], lb1 = slb[2 * cq + 1];

    // circular conv, packed channel pairs: acc[pc] = out2[pr*8+pc][{2cq,2cq+1}]
    f32x2 acc[8];
    #pragma unroll
    for (int pc = 0; pc < 8; ++pc) acc[pc] = (f32x2){0.f, 0.f};
    #pragma unroll
    for (int tr = 0; tr < 8; ++tr) {
        int rrow = (pr - tr) & 7;
        f32x2 kv[8];
        #pragma unroll
        for (int j = 0; j < 8; ++j)
            kv[j] = bfpair(*(const unsigned int*)&sk[(rrow * 8 + j) * 128 + cq * 2]);
        #pragma unroll
        for (int tc = 0; tc < 8; ++tc) {
            f32x2 qv = bfpair(*(const unsigned int*)&sq[(tr * 8 + tc) * 128 + cq * 2]);
            #pragma unroll
            for (int pc = 0; pc < 8; ++pc)
                acc[pc] += qv * kv[(pc - tc) & 7];
        }
    }
    __syncthreads();   // sq/sk reads done

    *(u32x4*)&sv[tid * 16]     = vreg0;
    *(u32x4*)&sv[tid * 16 + 8] = vreg1;

    // LN over 128 channels: DPP all-sum (VALU pipe)
    float mu[8], inv[8];
    #pragma unroll
    for (int pc = 0; pc < 8; ++pc) {
        float s  = wred_allsum(acc[pc].x + acc[pc].y);
        float s2 = wred_allsum(acc[pc].x * acc[pc].x + acc[pc].y * acc[pc].y);
        float m_ = s * (1.f / 128.f);
        mu[pc]  = m_;
        inv[pc] = rsqrtf(s2 * (1.f / 128.f) - m_ * m_ + 1e-5f);
    }
    __syncthreads();   // sv visible

    #pragma unroll
    for (int pc = 0; pc < 8; ++pc) {
        int px = pr * 8 + pc;
        unsigned int uv = *(const unsigned int*)&sv[px * 128 + cq * 2];
        float y0 = ((acc[pc].x - mu[pc]) * inv[pc] * lw0 + lb0) * bflo(uv);
        float y1 = ((acc[pc].y - mu[pc]) * inv[pc] * lw1 + lb1) * bfhi(uv);
        unsigned int pk = (unsigned int)f2bf(y0) | ((unsigned int)f2bf(y1) << 16);
        *(unsigned int*)&sy[px * 128 + (((cq >> 2) ^ (px & 7)) << 3) + 2 * (cq & 3)] = pk;
    }
    __syncthreads();

    {
        const int lane = tid & 63;
        const int l15 = lane & 15, l4 = lane >> 4;
        const int wave = tid >> 6;
        const int mt = wave >> 1;
        const int nt0 = 2 * (wave & 1);
        f32x4 pacc[2];
        pacc[0] = (f32x4){0.f, 0.f, 0.f, 0.f};
        pacc[1] = (f32x4){0.f, 0.f, 0.f, 0.f};
        const int px_a = mt * 16 + l15;
        #pragma unroll
        for (int ks = 0; ks < 4; ++ks) {
            int cch = ks * 4 + l4;
            bf16x8 af = *(const bf16x8*)&sy[px_a * 128 + ((cch ^ (px_a & 7)) << 3)];
            #pragma unroll
            for (int p2 = 0; p2 < 2; ++p2) {
                int o_n = (nt0 + p2) * 16 + l15;
                bf16x8 bfr = *(const bf16x8*)&swp[o_n * 128 + ((cch ^ (o_n & 7)) << 3)];
                pacc[p2] = __builtin_amdgcn_mfma_f32_16x16x32_bf16(af, bfr, pacc[p2], 0, 0, 0);
            }
        }
        #pragma unroll
        for (int p2 = 0; p2 < 2; ++p2)
            #pragma unroll
            for (int r = 0; r < 4; ++r) {
                int px = mt * 16 + l4 * 4 + r;
                int o = (nt0 + p2) * 16 + l15;
                sc[px * 64 + o] = pacc[p2][r];
            }
    }
    __syncthreads();

    {
        const int o = tid & 63, r = tid >> 6;
        float v0[4], v1[4];
        #pragma unroll
        for (int j = 0; j < 4; ++j) {
            v0[j] = sc[(r * 8 + j) * 64 + o];
            v1[j] = sc[(r * 8 + 4 + j) * 64 + o];
        }
        int obase = ((b * 64 + o) * 256 + h0 + r) * 256 + w0;
        *(f32x4*)&out[obase]     = (f32x4){v0[0], v0[1], v0[2], v0[3]};
        *(f32x4*)&out[obase + 4] = (f32x4){v1[0], v1[1], v1[2], v1[3]};
    }
}

extern "C" void kernel_launch(void* const* d_in, const int* in_sizes, int n_in,
                              void* d_out, int out_size, void* d_ws, size_t ws_size,
                              hipStream_t stream) {
    (void)in_sizes; (void)n_in; (void)out_size; (void)ws_size;
    const float* x        = (const float*)d_in[0];
    const float* evt      = (const float*)d_in[1];
    const float* w_q      = (const float*)d_in[2];
    const float* w_kv     = (const float*)d_in[3];
    const float* w_qdw    = (const float*)d_in[4];
    const float* w_kvdw   = (const float*)d_in[5];
    const float* w_proj   = (const float*)d_in[6];
    const float* ln_img_w = (const float*)d_in[7];
    const float* ln_img_b = (const float*)d_in[8];
    const float* ln_evt_w = (const float*)d_in[9];
    const float* ln_evt_b = (const float*)d_in[10];
    const float* ln_out_w = (const float*)d_in[11];
    const float* ln_out_b = (const float*)d_in[12];
    float* out = (float*)d_out;

    const size_t NPATCH = (size_t)4 * 32 * 32 * 8192;
    const size_t NLN    = (size_t)4 * 65536 * 64;
    unsigned short* qd  = (unsigned short*)d_ws;
    unsigned short* kd  = qd + NPATCH;
    unsigned short* eln = kd + NPATCH;
    unsigned short* xln = eln + NLN;
    unsigned short* vd  = xln;   // overlay: xln dead after prod-q

    dim3 lgrid(1024, 1, 2), lblk(256);
    ln_kernel<<<lgrid, lblk, 0, stream>>>(x, evt, ln_img_w, ln_img_b,
                                          ln_evt_w, ln_evt_b, xln, eln);
    dim3 grid(32, 32, 4), blk(512);
    prod_kernel<<<grid, blk, 0, stream>>>(xln, w_q,            w_qdw,           qd);
    prod_kernel<<<grid, blk, 0, stream>>>(eln, w_kv,           w_kvdw,          kd);
    prod_kernel<<<grid, blk, 0, stream>>>(eln, w_kv + 128*64,  w_kvdw + 128*9,  vd);
    patch_kernel<<<grid, blk, 0, stream>>>(qd, kd, vd, w_proj, ln_out_w, ln_out_b, out);
}

// Round 7
// 264.699 us; speedup vs baseline: 2.5022x; 1.0728x over previous
//
#include <hip/hip_runtime.h>

typedef __attribute__((ext_vector_type(8))) short bf16x8;
typedef __attribute__((ext_vector_type(4))) float f32x4;
typedef __attribute__((ext_vector_type(2))) float f32x2;
typedef __attribute__((ext_vector_type(4))) unsigned int u32x4;
typedef __attribute__((ext_vector_type(2))) unsigned int u32x2;

__device__ __forceinline__ unsigned short f2bf(float f) {
    union { float f; unsigned int u; } v; v.f = f;
    return (unsigned short)((v.u + 0x7fffu + ((v.u >> 16) & 1u)) >> 16);
}
__device__ __forceinline__ float bflo(unsigned int u) {
    union { unsigned int u; float f; } v; v.u = u << 16; return v.f;
}
__device__ __forceinline__ float bfhi(unsigned int u) {
    union { unsigned int u; float f; } v; v.u = u & 0xffff0000u; return v.f;
}
__device__ __forceinline__ f32x2 bfpair(unsigned int u) {
    union { unsigned int u; float f; } lo, hi;
    lo.u = u << 16; hi.u = u & 0xffff0000u;
    return (f32x2){lo.f, hi.f};
}

// gfx9 64-lane all-sum via DPP (VALU pipe, not LDS pipe).
__device__ __forceinline__ float wred_allsum(float x) {
    asm volatile(
        "s_nop 1\n\t"
        "v_add_f32_dpp %0, %0, %0 row_shr:1 bound_ctrl:0\n\t"
        "s_nop 1\n\t"
        "v_add_f32_dpp %0, %0, %0 row_shr:2 bound_ctrl:0\n\t"
        "s_nop 1\n\t"
        "v_add_f32_dpp %0, %0, %0 row_shr:4 bound_ctrl:0\n\t"
        "s_nop 1\n\t"
        "v_add_f32_dpp %0, %0, %0 row_shr:8 bound_ctrl:0\n\t"
        "s_nop 1\n\t"
        "v_add_f32_dpp %0, %0, %0 row_bcast:15 row_mask:0xa bound_ctrl:0\n\t"
        "s_nop 1\n\t"
        "v_add_f32_dpp %0, %0, %0 row_bcast:31 row_mask:0xc bound_ctrl:0\n\t"
        "s_nop 1"
        : "+v"(x));
    return __builtin_bit_cast(float, __builtin_amdgcn_readlane(__builtin_bit_cast(int, x), 63));
}

// ---------------------------------------------------------------------------
// K1: channel LayerNorm, NCHW fp32 -> NHWC bf16, via LDS transpose.
// Block: 64 contiguous hw pixels x 64 channels. No big register arrays.
// ---------------------------------------------------------------------------
__global__ __launch_bounds__(256, 8)
void ln_kernel(const float* __restrict__ x, const float* __restrict__ evt,
               const float* __restrict__ lwx, const float* __restrict__ lbx,
               const float* __restrict__ lwe, const float* __restrict__ lbe,
               unsigned short* __restrict__ xo, unsigned short* __restrict__ eo)
{
    __shared__ float xt[64][68];
    __shared__ float ps[4][64], ps2[4][64];
    __shared__ float smu[64], sinv[64], slw[64], slb[64];

    const int tid = threadIdx.x;
    const int z = blockIdx.z, b = blockIdx.y;
    const int hw0 = blockIdx.x * 64;
    const float* src = z ? evt : x;
    const float* lw  = z ? lwe : lwx;
    const float* lb  = z ? lbe : lbx;
    unsigned short* dst = z ? eo : xo;

    if (tid < 64) { slw[tid] = lw[tid]; slb[tid] = lb[tid]; }

    const float* sp = src + (size_t)b * 64 * 65536 + hw0;
    #pragma unroll
    for (int it = 0; it < 4; ++it) {
        int i = tid + it * 256;
        int c = i >> 4, p4 = i & 15;          // coalesced: lanes sweep p4
        f32x4 v = *(const f32x4*)&sp[(size_t)c * 65536 + p4 * 4];
        xt[p4 * 4 + 0][c] = v.x;
        xt[p4 * 4 + 1][c] = v.y;
        xt[p4 * 4 + 2][c] = v.z;
        xt[p4 * 4 + 3][c] = v.w;
    }
    __syncthreads();

    {   // per-pixel partial stats over 16 channels each
        int px = tid & 63, part = tid >> 6;
        float s = 0.f, s2 = 0.f;
        #pragma unroll
        for (int j = 0; j < 4; ++j) {
            f32x4 v = *(const f32x4*)&xt[px][part * 16 + j * 4];
            s  += v.x + v.y + v.z + v.w;
            s2 += v.x * v.x + v.y * v.y + v.z * v.z + v.w * v.w;
        }
        ps[part][px] = s; ps2[part][px] = s2;
    }
    __syncthreads();
    if (tid < 64) {
        float s  = ps[0][tid] + ps[1][tid] + ps[2][tid] + ps[3][tid];
        float s2 = ps2[0][tid] + ps2[1][tid] + ps2[2][tid] + ps2[3][tid];
        float mu = s * (1.f / 64.f);
        smu[tid] = mu;
        sinv[tid] = rsqrtf(s2 * (1.f / 64.f) - mu * mu + 1e-5f);
    }
    __syncthreads();

    unsigned short* dp = dst + ((size_t)b * 65536 + hw0) * 64;
    #pragma unroll
    for (int it = 0; it < 2; ++it) {
        int i = tid + it * 256;
        int px = i >> 3, oct = i & 7;
        float mu = smu[px], inv = sinv[px];
        f32x4 v0 = *(const f32x4*)&xt[px][oct * 8];
        f32x4 v1 = *(const f32x4*)&xt[px][oct * 8 + 4];
        u32x4 w;
        int c = oct * 8;
        float a0 = (v0.x - mu) * inv * slw[c + 0] + slb[c + 0];
        float a1 = (v0.y - mu) * inv * slw[c + 1] + slb[c + 1];
        w[0] = (unsigned int)f2bf(a0) | ((unsigned int)f2bf(a1) << 16);
        a0 = (v0.z - mu) * inv * slw[c + 2] + slb[c + 2];
        a1 = (v0.w - mu) * inv * slw[c + 3] + slb[c + 3];
        w[1] = (unsigned int)f2bf(a0) | ((unsigned int)f2bf(a1) << 16);
        a0 = (v1.x - mu) * inv * slw[c + 4] + slb[c + 4];
        a1 = (v1.y - mu) * inv * slw[c + 5] + slb[c + 5];
        w[2] = (unsigned int)f2bf(a0) | ((unsigned int)f2bf(a1) << 16);
        a0 = (v1.z - mu) * inv * slw[c + 6] + slb[c + 6];
        a1 = (v1.w - mu) * inv * slw[c + 7] + slb[c + 7];
        w[3] = (unsigned int)f2bf(a0) | ((unsigned int)f2bf(a1) << 16);
        *(u32x4*)&dp[(size_t)px * 64 + oct * 8] = w;   // 8px x 128B coalesced
    }
}

// ---------------------------------------------------------------------------
// K2: producer: conv1x1 (MFMA bf16, 128 out) + depthwise 3x3 (ring + pk_fma).
// In-kernel weight staging from fp32 (proven R5 path).
// ---------------------------------------------------------------------------
#define PR_WB    14336
#define PR_WDW   30720
#define PR_SMEM  35328

__global__ __launch_bounds__(512, 8)
void prod_kernel(const unsigned short* __restrict__ src,
                 const float* __restrict__ wmat, const float* __restrict__ wdw,
                 unsigned short* __restrict__ dst)
{
    __shared__ __align__(16) char smem[PR_SMEM];
    unsigned short* A   = (unsigned short*)(smem);
    unsigned short* Wb  = (unsigned short*)(smem + PR_WB);
    unsigned short* pre = (unsigned short*)(smem);          // overlays A+Wb
    float* swdw = (float*)(smem + PR_WDW);

    const int tid = threadIdx.x;
    const int pj = blockIdx.x, pi = blockIdx.y, b = blockIdx.z;
    const int h0 = pi * 8, w0 = pj * 8;

    #pragma unroll
    for (int it = 0; it < 4; ++it) {
        int i = tid + it * 512;
        int o = i >> 4, c4 = i & 15;
        f32x4 wv = *(const f32x4*)&wmat[o * 64 + c4 * 4];
        unsigned int lo = (unsigned int)f2bf(wv[0]) | ((unsigned int)f2bf(wv[1]) << 16);
        unsigned int hi = (unsigned int)f2bf(wv[2]) | ((unsigned int)f2bf(wv[3]) << 16);
        u32x2 pk = {lo, hi};
        *(u32x2*)&Wb[o * 64 + (((c4 >> 1) ^ (o & 7)) << 3) + (c4 & 1) * 4] = pk;
    }
    for (int i = tid; i < 1152; i += 512) swdw[i] = wdw[i];
    for (int i = tid; i < 768; i += 512) A[6400 + i] = 0;
    #pragma unroll
    for (int it = 0; it < 2; ++it) {
        int i = tid + it * 512;
        if (i < 800) {
            int px = i >> 3, oct = i & 7;
            int r = px / 10, cc = px - r * 10;
            int gh = h0 - 1 + r, gw = w0 - 1 + cc;
            u32x4 val = {0u, 0u, 0u, 0u};
            if (gh >= 0 && gh < 256 && gw >= 0 && gw < 256)
                val = *(const u32x4*)&src[((size_t)(b * 65536 + gh * 256 + gw)) * 64 + oct * 8];
            *(u32x4*)&A[px * 64 + ((oct ^ (px & 7)) << 3)] = val;
        }
    }
    __syncthreads();

    // MFMA: [112px x 64c] x [64c x 128o]
    const int lane = tid & 63;
    const int l15 = lane & 15, l4 = lane >> 4;
    const int o_n = (tid >> 6) * 16 + l15;
    f32x4 acc[7];
    #pragma unroll
    for (int mt = 0; mt < 7; ++mt) acc[mt] = (f32x4){0.f, 0.f, 0.f, 0.f};
    #pragma unroll
    for (int ks = 0; ks < 2; ++ks) {
        int cch = ks * 4 + l4;
        bf16x8 bfrag = *(const bf16x8*)&Wb[o_n * 64 + ((cch ^ (o_n & 7)) << 3)];
        #pragma unroll
        for (int mt = 0; mt < 7; ++mt) {
            int px = mt * 16 + l15;
            bf16x8 afrag = *(const bf16x8*)&A[px * 64 + ((cch ^ (px & 7)) << 3)];
            acc[mt] = __builtin_amdgcn_mfma_f32_16x16x32_bf16(afrag, bfrag, acc[mt], 0, 0, 0);
        }
    }
    __syncthreads();   // A/Wb reads done -> pre may overlay

    #pragma unroll
    for (int mt = 0; mt < 7; ++mt)
        #pragma unroll
        for (int r = 0; r < 4; ++r) {
            int px = mt * 16 + l4 * 4 + r;
            if (px < 100)
                pre[px * 128 + (((o_n >> 3) ^ (px & 7)) << 3) + (o_n & 7)] = f2bf(acc[mt][r]);
        }
    __syncthreads();

    // depthwise 3x3: thread = (o-pair, pixel column); 10-row ring, pk_fma
    {
        const int o = (tid & 63) * 2;
        const int och = o >> 3, osub = o & 7;
        const int pc = tid >> 6;
        f32x2 wdp[9];
        #pragma unroll
        for (int t = 0; t < 9; ++t)
            wdp[t] = (f32x2){swdw[o * 9 + t], swdw[o * 9 + 9 + t]};
        const size_t patchbase = ((size_t)(b * 32 + pi) * 32 + pj) * 8192;

        f32x2 ra[3], rb[3], rc[3];
        #define LOADROW(dstv, rr)                                                        \
            {                                                                            \
                _Pragma("unroll")                                                        \
                for (int d = 0; d < 3; ++d) {                                            \
                    int hp = (rr) * 10 + pc + d;                                         \
                    unsigned int u = *(const unsigned int*)                              \
                        &pre[hp * 128 + ((och ^ (hp & 7)) << 3) + osub];                 \
                    dstv[d] = bfpair(u);                                                 \
                }                                                                        \
            }
        LOADROW(ra, 0)
        LOADROW(rb, 1)
        #pragma unroll
        for (int r = 2; r < 10; ++r) {
            LOADROW(rc, r)
            f32x2 s = ra[0] * wdp[0];
            s += ra[1] * wdp[1]; s += ra[2] * wdp[2];
            s += rb[0] * wdp[3]; s += rb[1] * wdp[4]; s += rb[2] * wdp[5];
            s += rc[0] * wdp[6]; s += rc[1] * wdp[7]; s += rc[2] * wdp[8];
            int px = (r - 2) * 8 + pc;
            unsigned int outw = (unsigned int)f2bf(s.x) | ((unsigned int)f2bf(s.y) << 16);
            *(unsigned int*)&dst[patchbase + px * 128 + o] = outw;
            #pragma unroll
            for (int d = 0; d < 3; ++d) { ra[d] = rb[d]; rb[d] = rc[d]; }
        }
        #undef LOADROW
    }
}

// ---------------------------------------------------------------------------
// K3: patch kernel: circular conv (pk_fma) + LN(128) via DPP + *v + proj MFMA
// ---------------------------------------------------------------------------
#define PK_Q    0
#define PK_K    16384
#define PK_WP   32768
#define PK_LW   49152
#define PK_LB   49664
#define PK_SMEM 50176

__global__ __launch_bounds__(512, 6)
void patch_kernel(const unsigned short* __restrict__ qb,
                  const unsigned short* __restrict__ kb,
                  const unsigned short* __restrict__ vb,
                  const float* __restrict__ w_proj,
                  const float* __restrict__ lnw, const float* __restrict__ lnb,
                  float* __restrict__ out)
{
    __shared__ __align__(16) char smem[PK_SMEM];
    unsigned short* sq  = (unsigned short*)(smem + PK_Q);
    unsigned short* sk  = (unsigned short*)(smem + PK_K);
    unsigned short* sy  = sq;
    unsigned short* sv  = sk;
    float*          sc  = (float*)(smem + PK_K);
    unsigned short* swp = (unsigned short*)(smem + PK_WP);
    float* slw = (float*)(smem + PK_LW);
    float* slb = (float*)(smem + PK_LB);

    const int tid = threadIdx.x;
    const int tj = blockIdx.x, ti = blockIdx.y, b = blockIdx.z;
    const int h0 = ti * 8, w0 = tj * 8;
    const size_t pbase = ((size_t)(b * 32 + ti) * 32 + tj) * 8192;

    u32x4 vreg0 = *(const u32x4*)&vb[pbase + tid * 16];
    u32x4 vreg1 = *(const u32x4*)&vb[pbase + tid * 16 + 8];

    if (tid < 128) { slw[tid] = lnw[tid]; slb[tid] = lnb[tid]; }
    #pragma unroll
    for (int it = 0; it < 2; ++it) {
        int i = tid + it * 512;
        *(u32x4*)&sq[i * 8] = *(const u32x4*)&qb[pbase + i * 8];
        *(u32x4*)&sk[i * 8] = *(const u32x4*)&kb[pbase + i * 8];
    }
    #pragma unroll
    for (int it = 0; it < 4; ++it) {
        int i = tid + it * 512;
        int o = i >> 5, c4 = i & 31;
        f32x4 wv = *(const f32x4*)&w_proj[o * 128 + c4 * 4];
        unsigned int lo = (unsigned int)f2bf(wv[0]) | ((unsigned int)f2bf(wv[1]) << 16);
        unsigned int hi = (unsigned int)f2bf(wv[2]) | ((unsigned int)f2bf(wv[3]) << 16);
        u32x2 pk = {lo, hi};
        *(u32x2*)&swp[o * 128 + (((c4 >> 1) ^ (o & 7)) << 3) + (c4 & 1) * 4] = pk;
    }
    __syncthreads();

    const int pr = tid >> 6;
    const int cq = tid & 63;
    const float lw0 = slw[2 * cq], lw1 = slw[2 * cq + 1];
    const float lb0 = slb[2 * cq], lb1 = slb[2 * cq + 1];

    f32x2 acc[8];
    #pragma unroll
    for (int pc = 0; pc < 8; ++pc) acc[pc] = (f32x2){0.f, 0.f};
    #pragma unroll
    for (int tr = 0; tr < 8; ++tr) {
        int rrow = (pr - tr) & 7;
        f32x2 kv[8];
        #pragma unroll
        for (int j = 0; j < 8; ++j)
            kv[j] = bfpair(*(const unsigned int*)&sk[(rrow * 8 + j) * 128 + cq * 2]);
        #pragma unroll
        for (int tc = 0; tc < 8; ++tc) {
            f32x2 qv = bfpair(*(const unsigned int*)&sq[(tr * 8 + tc) * 128 + cq * 2]);
            #pragma unroll
            for (int pc = 0; pc < 8; ++pc)
                acc[pc] += qv * kv[(pc - tc) & 7];
        }
    }
    __syncthreads();

    *(u32x4*)&sv[tid * 16]     = vreg0;
    *(u32x4*)&sv[tid * 16 + 8] = vreg1;

    float mu[8], inv[8];
    #pragma unroll
    for (int pc = 0; pc < 8; ++pc) {
        float s  = wred_allsum(acc[pc].x + acc[pc].y);
        float s2 = wred_allsum(acc[pc].x * acc[pc].x + acc[pc].y * acc[pc].y);
        float m_ = s * (1.f / 128.f);
        mu[pc]  = m_;
        inv[pc] = rsqrtf(s2 * (1.f / 128.f) - m_ * m_ + 1e-5f);
    }
    __syncthreads();

    #pragma unroll
    for (int pc = 0; pc < 8; ++pc) {
        int px = pr * 8 + pc;
        unsigned int uv = *(const unsigned int*)&sv[px * 128 + cq * 2];
        float y0 = ((acc[pc].x - mu[pc]) * inv[pc] * lw0 + lb0) * bflo(uv);
        float y1 = ((acc[pc].y - mu[pc]) * inv[pc] * lw1 + lb1) * bfhi(uv);
        unsigned int pk = (unsigned int)f2bf(y0) | ((unsigned int)f2bf(y1) << 16);
        *(unsigned int*)&sy[px * 128 + (((cq >> 2) ^ (px & 7)) << 3) + 2 * (cq & 3)] = pk;
    }
    __syncthreads();

    {
        const int lane = tid & 63;
        const int l15 = lane & 15, l4 = lane >> 4;
        const int wave = tid >> 6;
        const int mt = wave >> 1;
        const int nt0 = 2 * (wave & 1);
        f32x4 pacc[2];
        pacc[0] = (f32x4){0.f, 0.f, 0.f, 0.f};
        pacc[1] = (f32x4){0.f, 0.f, 0.f, 0.f};
        const int px_a = mt * 16 + l15;
        #pragma unroll
        for (int ks = 0; ks < 4; ++ks) {
            int cch = ks * 4 + l4;
            bf16x8 af = *(const bf16x8*)&sy[px_a * 128 + ((cch ^ (px_a & 7)) << 3)];
            #pragma unroll
            for (int p2 = 0; p2 < 2; ++p2) {
                int o_n = (nt0 + p2) * 16 + l15;
                bf16x8 bfr = *(const bf16x8*)&swp[o_n * 128 + ((cch ^ (o_n & 7)) << 3)];
                pacc[p2] = __builtin_amdgcn_mfma_f32_16x16x32_bf16(af, bfr, pacc[p2], 0, 0, 0);
            }
        }
        #pragma unroll
        for (int p2 = 0; p2 < 2; ++p2)
            #pragma unroll
            for (int r = 0; r < 4; ++r) {
                int px = mt * 16 + l4 * 4 + r;
                int o = (nt0 + p2) * 16 + l15;
                sc[px * 64 + o] = pacc[p2][r];
            }
    }
    __syncthreads();

    {
        const int o = tid & 63, r = tid >> 6;
        float v0[4], v1[4];
        #pragma unroll
        for (int j = 0; j < 4; ++j) {
            v0[j] = sc[(r * 8 + j) * 64 + o];
            v1[j] = sc[(r * 8 + 4 + j) * 64 + o];
        }
        int obase = ((b * 64 + o) * 256 + h0 + r) * 256 + w0;
        *(f32x4*)&out[obase]     = (f32x4){v0[0], v0[1], v0[2], v0[3]};
        *(f32x4*)&out[obase + 4] = (f32x4){v1[0], v1[1], v1[2], v1[3]};
    }
}

extern "C" void kernel_launch(void* const* d_in, const int* in_sizes, int n_in,
                              void* d_out, int out_size, void* d_ws, size_t ws_size,
                              hipStream_t stream) {
    (void)in_sizes; (void)n_in; (void)out_size; (void)ws_size;
    const float* x        = (const float*)d_in[0];
    const float* evt      = (const float*)d_in[1];
    const float* w_q      = (const float*)d_in[2];
    const float* w_kv     = (const float*)d_in[3];
    const float* w_qdw    = (const float*)d_in[4];
    const float* w_kvdw   = (const float*)d_in[5];
    const float* w_proj   = (const float*)d_in[6];
    const float* ln_img_w = (const float*)d_in[7];
    const float* ln_img_b = (const float*)d_in[8];
    const float* ln_evt_w = (const float*)d_in[9];
    const float* ln_evt_b = (const float*)d_in[10];
    const float* ln_out_w = (const float*)d_in[11];
    const float* ln_out_b = (const float*)d_in[12];
    float* out = (float*)d_out;

    // Workspace layout (ushorts) — R5-proven 224 MiB footprint, nothing after vd:
    //   qd [0,64MiB) kd [64,128) eln [128,160) xln [160,192) vd=xln overlay [160,224)
    const size_t NPATCH = (size_t)4 * 32 * 32 * 8192;
    const size_t NLN    = (size_t)4 * 65536 * 64;
    unsigned short* qd  = (unsigned short*)d_ws;
    unsigned short* kd  = qd + NPATCH;
    unsigned short* eln = kd + NPATCH;
    unsigned short* xln = eln + NLN;
    unsigned short* vd  = xln;   // overlay: xln dead after prod-q; vd extends past it

    dim3 lgrid(1024, 4, 2), lblk(256);
    ln_kernel<<<lgrid, lblk, 0, stream>>>(x, evt, ln_img_w, ln_img_b,
                                          ln_evt_w, ln_evt_b, xln, eln);
    dim3 grid(32, 32, 4), blk(512);
    prod_kernel<<<grid, blk, 0, stream>>>(xln, w_q,            w_qdw,           qd);
    prod_kernel<<<grid, blk, 0, stream>>>(eln, w_kv,           w_kvdw,          kd);
    prod_kernel<<<grid, blk, 0, stream>>>(eln, w_kv + 128*64,  w_kvdw + 128*9,  vd);
    patch_kernel<<<grid, blk, 0, stream>>>(qd, kd, vd, w_proj, ln_out_w, ln_out_b, out);
}